// Round 26
// baseline (400.204 us; speedup 1.0000x reference)
//
#include <hip/hip_runtime.h>
#include <hip/hip_bf16.h>
#include <cstdint>

#define NODES  65536
#define CH     128
#define NGRAPH 1024
#define PGRAPH 64
#define FCO    65536

typedef __bf16 bf16x8 __attribute__((ext_vector_type(8)));
typedef __bf16 bf16x4 __attribute__((ext_vector_type(4)));
typedef float  f32x4  __attribute__((ext_vector_type(4)));

__device__ __forceinline__ float bflo(unsigned u){ return __uint_as_float(u << 16); }
__device__ __forceinline__ float bfhi(unsigned u){ return __uint_as_float(u & 0xffff0000u); }

// ---------------- graph preprocessing ----------------

__global__ void k_zero1(int* __restrict__ a){
  const int i = blockIdx.x*256 + threadIdx.x;
  ((int4*)a)[i] = make_int4(0,0,0,0);
}

__global__ void k_degree(const int* __restrict__ dst, int* __restrict__ deg, int E){
  int e = blockIdx.x*256 + threadIdx.x;
  if (e < E) atomicAdd(&deg[dst[e]], 1);
}

// scan1 also emits dinv (deg is final here) — replaces the separate k_dinv launch
__global__ void k_scan1(const int* __restrict__ deg, int* __restrict__ excl,
                        int* __restrict__ bsums, float* __restrict__ dinv){
  __shared__ int tmp[256];
  const int t = threadIdx.x;
  const int gid = blockIdx.x*256 + t;
  const int v = deg[gid];
  dinv[gid] = 1.0f / sqrtf((float)(v + 1));   // self-loop -> deg+1 >= 1
  tmp[t] = v;
  __syncthreads();
  #pragma unroll
  for (int off = 1; off < 256; off <<= 1){
    int x = (t >= off) ? tmp[t-off] : 0;
    __syncthreads();
    tmp[t] += x;
    __syncthreads();
  }
  excl[gid] = tmp[t] - v;
  if (t == 255) bsums[blockIdx.x] = tmp[255];
}

__global__ void k_scan2(int* __restrict__ bsums){
  __shared__ int tmp[256];
  const int t = threadIdx.x;
  const int v = bsums[t];
  tmp[t] = v;
  __syncthreads();
  #pragma unroll
  for (int off = 1; off < 256; off <<= 1){
    int x = (t >= off) ? tmp[t-off] : 0;
    __syncthreads();
    tmp[t] += x;
    __syncthreads();
  }
  bsums[t] = tmp[t] - v;   // exclusive
}

__global__ void k_scan3(int* __restrict__ cstart, const int* __restrict__ bsums, int E){
  const int gid = blockIdx.x*256 + threadIdx.x;
  cstart[gid] += bsums[blockIdx.x];
  if (gid == 0) cstart[NODES] = E;
}

// scatter atomicAdds DIRECTLY on cstart -> afterwards cstart[d] = end offset.
// k_agg recovers start = end - deg[d] (deg preserved). cursor buffer eliminated.
__global__ void k_scatter(const int* __restrict__ src, const int* __restrict__ dst,
                          int* __restrict__ cstart, int* __restrict__ ssrc, int E){
  int e = blockIdx.x*256 + threadIdx.x;
  if (e >= E) return;
  const int d = dst[e];
  const int p = atomicAdd(&cstart[d], 1);
  ssrc[p] = src[e];
}

// ---------------- GEMM: C[n x 128] = A[n x 128] @ W[128 x 128], bf16 out ----------
template<int ABF>
__global__ __launch_bounds__(256)
void k_gemm128(const void* __restrict__ Av, const float* __restrict__ W,
               __bf16* __restrict__ Cout){
  __shared__ float As[128][36];
  __shared__ float Ws[32][160];
  const int t  = threadIdx.x;
  const int r0 = blockIdx.x * 128;
  const int q  = t & 3;
  const int rp = t >> 2;

  float acc0[32], acc1[32];
  #pragma unroll
  for (int j = 0; j < 32; ++j){ acc0[j] = 0.f; acc1[j] = 0.f; }

  for (int kc = 0; kc < 128; kc += 32){
    {
      const int row = t >> 1, u = t & 1;
      float* asp = &As[row][u*16];
      if (ABF){
        const __bf16* ap = (const __bf16*)Av + (size_t)(r0+row)*CH + kc + u*16;
        const bf16x8 v0 = *(const bf16x8*)ap;
        const bf16x8 v1 = *(const bf16x8*)(ap + 8);
        #pragma unroll
        for (int j = 0; j < 8; ++j){ asp[j] = (float)v0[j]; asp[8+j] = (float)v1[j]; }
      } else {
        const float* ap = (const float*)Av + (size_t)(r0+row)*CH + kc + u*16;
        #pragma unroll
        for (int i = 0; i < 4; ++i)
          *(float4*)(asp + 4*i) = *(const float4*)(ap + 4*i);
      }
    }
    {
      const int kk = t >> 3, u = t & 7;
      const float* wp = W + (size_t)(kc+kk)*CH + u*16;
      float* wsp = &Ws[kk][(u>>1)*40 + (u&1)*16];
      #pragma unroll
      for (int i = 0; i < 4; ++i)
        *(float4*)(wsp + 4*i) = *(const float4*)(wp + 4*i);
    }
    __syncthreads();

    #pragma unroll
    for (int kk4 = 0; kk4 < 8; ++kk4){
      const float4 a0 = *(const float4*)&As[rp][kk4*4];
      const float4 a1 = *(const float4*)&As[rp+64][kk4*4];
      const float a0f[4] = {a0.x, a0.y, a0.z, a0.w};
      const float a1f[4] = {a1.x, a1.y, a1.z, a1.w};
      #pragma unroll
      for (int kk = 0; kk < 4; ++kk){
        const float av0 = a0f[kk], av1 = a1f[kk];
        #pragma unroll
        for (int j4 = 0; j4 < 8; ++j4){
          const float4 w = *(const float4*)&Ws[kk4*4+kk][q*40 + j4*4];
          acc0[j4*4+0] = fmaf(av0, w.x, acc0[j4*4+0]);
          acc0[j4*4+1] = fmaf(av0, w.y, acc0[j4*4+1]);
          acc0[j4*4+2] = fmaf(av0, w.z, acc0[j4*4+2]);
          acc0[j4*4+3] = fmaf(av0, w.w, acc0[j4*4+3]);
          acc1[j4*4+0] = fmaf(av1, w.x, acc1[j4*4+0]);
          acc1[j4*4+1] = fmaf(av1, w.y, acc1[j4*4+1]);
          acc1[j4*4+2] = fmaf(av1, w.z, acc1[j4*4+2]);
          acc1[j4*4+3] = fmaf(av1, w.w, acc1[j4*4+3]);
        }
      }
    }
    __syncthreads();
  }

  __bf16* c0 = Cout + (size_t)(r0+rp)*CH    + q*32;
  __bf16* c1 = Cout + (size_t)(r0+rp+64)*CH + q*32;
  #pragma unroll
  for (int j4 = 0; j4 < 8; ++j4){
    bf16x4 v0, v1;
    #pragma unroll
    for (int e = 0; e < 4; ++e){ v0[e] = (__bf16)acc0[j4*4+e]; v1[e] = (__bf16)acc1[j4*4+e]; }
    *(bf16x4*)(c0 + j4*4) = v0;
    *(bf16x4*)(c1 + j4*4) = v1;
  }
}

// ---------------- CSR aggregation, fused bias+relu, bf16 in/out ----------
// start = cend[i] - deg[i]  (cend = post-scatter cstart holding end offsets).
__global__ __launch_bounds__(256)
void k_agg(const __bf16* __restrict__ hw, const float* __restrict__ dinv,
           const int* __restrict__ cend, const int* __restrict__ deg,
           const int* __restrict__ srcs,
           const float* __restrict__ bias, __bf16* __restrict__ outp){
  const int l = threadIdx.x & 63, wave = threadIdx.x >> 6;
  const int n = l >> 4;                    // sub-node 0..3
  const int q = l & 15;                    // lane within node
  const int i = blockIdx.x*16 + wave*4 + n;
  const int c = q*8;
  const float di = dinv[i];

  const uint4 hs = *(const uint4*)&hw[(size_t)i*CH + c];
  float acc[8];
  acc[0] = di*bflo(hs.x); acc[1] = di*bfhi(hs.x);
  acc[2] = di*bflo(hs.y); acc[3] = di*bfhi(hs.y);
  acc[4] = di*bflo(hs.z); acc[5] = di*bfhi(hs.z);
  acc[6] = di*bflo(hs.w); acc[7] = di*bfhi(hs.w);

  const int p1 = cend[i];
  int p = p1 - deg[i];
  for (; p + 3 < p1; p += 4){
    const int s0 = srcs[p], s1 = srcs[p+1], s2 = srcs[p+2], s3 = srcs[p+3];
    const float w0 = dinv[s0], w1 = dinv[s1], w2 = dinv[s2], w3 = dinv[s3];
    const uint4 r0 = *(const uint4*)&hw[(size_t)s0*CH + c];
    const uint4 r1 = *(const uint4*)&hw[(size_t)s1*CH + c];
    const uint4 r2 = *(const uint4*)&hw[(size_t)s2*CH + c];
    const uint4 r3 = *(const uint4*)&hw[(size_t)s3*CH + c];
    acc[0]+=w0*bflo(r0.x); acc[1]+=w0*bfhi(r0.x); acc[2]+=w0*bflo(r0.y); acc[3]+=w0*bfhi(r0.y);
    acc[4]+=w0*bflo(r0.z); acc[5]+=w0*bfhi(r0.z); acc[6]+=w0*bflo(r0.w); acc[7]+=w0*bfhi(r0.w);
    acc[0]+=w1*bflo(r1.x); acc[1]+=w1*bfhi(r1.x); acc[2]+=w1*bflo(r1.y); acc[3]+=w1*bfhi(r1.y);
    acc[4]+=w1*bflo(r1.z); acc[5]+=w1*bfhi(r1.z); acc[6]+=w1*bflo(r1.w); acc[7]+=w1*bfhi(r1.w);
    acc[0]+=w2*bflo(r2.x); acc[1]+=w2*bfhi(r2.x); acc[2]+=w2*bflo(r2.y); acc[3]+=w2*bfhi(r2.y);
    acc[4]+=w2*bflo(r2.z); acc[5]+=w2*bfhi(r2.z); acc[6]+=w2*bflo(r2.w); acc[7]+=w2*bfhi(r2.w);
    acc[0]+=w3*bflo(r3.x); acc[1]+=w3*bfhi(r3.x); acc[2]+=w3*bflo(r3.y); acc[3]+=w3*bfhi(r3.y);
    acc[4]+=w3*bflo(r3.z); acc[5]+=w3*bfhi(r3.z); acc[6]+=w3*bflo(r3.w); acc[7]+=w3*bfhi(r3.w);
  }
  for (; p < p1; ++p){
    const int s = srcs[p];
    const float w = dinv[s];
    const uint4 r = *(const uint4*)&hw[(size_t)s*CH + c];
    acc[0]+=w*bflo(r.x); acc[1]+=w*bfhi(r.x); acc[2]+=w*bflo(r.y); acc[3]+=w*bfhi(r.y);
    acc[4]+=w*bflo(r.z); acc[5]+=w*bfhi(r.z); acc[6]+=w*bflo(r.w); acc[7]+=w*bfhi(r.w);
  }

  const float4 b0 = *(const float4*)&bias[c];
  const float4 b1 = *(const float4*)&bias[c+4];
  const float bb[8] = {b0.x,b0.y,b0.z,b0.w,b1.x,b1.y,b1.z,b1.w};
  bf16x8 o;
  #pragma unroll
  for (int k = 0; k < 8; ++k)
    o[k] = (__bf16)fmaxf(di*acc[k] + bb[k], 0.f);
  *(bf16x8*)&outp[(size_t)i*CH + c] = o;
}

// ---------------- pool: pooled[g] = mean over 64 nodes (relu already applied) ------
__global__ void k_pool(const __bf16* __restrict__ h,
                       __bf16* __restrict__ phi, __bf16* __restrict__ plo){
  const int g = blockIdx.x, c = threadIdx.x;
  float acc = 0.f;
  const __bf16* hp = h + (size_t)g*PGRAPH*CH + c;
  #pragma unroll 4
  for (int i = 0; i < PGRAPH; ++i) acc += (float)hp[i*CH];
  const float v = acc * (1.0f/64.0f);
  const __bf16 hv = (__bf16)v;
  phi[g*CH + c] = hv;
  plo[g*CH + c] = (__bf16)(v - (float)hv);
}

// ---------------- Wfc -> split-bf16 in FRAGMENT order (tile stride 2048) ----------------
__global__ __launch_bounds__(256)
void k_cvt_wfc(const float* __restrict__ Wfc, __bf16* __restrict__ wth,
               __bf16* __restrict__ wtl){
  __shared__ float ls[128][65];
  const int t  = threadIdx.x;
  const int c0 = blockIdx.x*64;

  #pragma unroll 8
  for (int it = 0; it < 32; ++it){
    const int row = it*4 + (t>>6);
    ls[row][t&63] = Wfc[(size_t)row*FCO + c0 + (t&63)];
  }
  __syncthreads();

  const int col = t>>2, q = t&3;
  const int tg  = (c0>>4) + (col>>4);
  const int lc  = col & 15;
  __bf16* dh = wth + (size_t)tg*2048 + q*512 + lc*8;
  __bf16* dl = wtl + (size_t)tg*2048 + q*512 + lc*8;
  #pragma unroll
  for (int i = 0; i < 4; ++i){
    bf16x8 h8, l8;
    #pragma unroll
    for (int j = 0; j < 8; ++j){
      const float v = ls[q*32 + i*8 + j][col];
      const __bf16 hv = (__bf16)v;
      h8[j] = hv;
      l8[j] = (__bf16)(v - (float)hv);
    }
    *(bf16x8*)(dh + i*128) = h8;
    *(bf16x8*)(dl + i*128) = l8;
  }
}

// ---------------- FC via split-bf16 MFMA, 32 graphs/wave + LDS-staged stores --------
__global__ __launch_bounds__(256, 4)
void k_fc_mfma(const __bf16* __restrict__ phi, const __bf16* __restrict__ plo,
               const __bf16* __restrict__ wth, const __bf16* __restrict__ wtl,
               const float* __restrict__ bfc, float* __restrict__ out){
  __shared__ float st[4][32][68];                 // 34.8 KB
  const int t    = threadIdx.x;
  const int lane = t & 63, wave = t >> 6;
  const int lc   = lane & 15, kq = lane >> 4;
  const int g0   = blockIdx.x*32;                 // x = graph-tile (fast dim)
  const int c0w  = blockIdx.y*2048 + wave*512;    // y = col-range

  bf16x8 ah[2][4], al[2][4];                      // 64 VGPR
  #pragma unroll
  for (int gt = 0; gt < 2; ++gt){
    const __bf16* pa = phi + (size_t)(g0 + gt*16 + lc)*CH + kq*8;
    const __bf16* pb = plo + (size_t)(g0 + gt*16 + lc)*CH + kq*8;
    #pragma unroll
    for (int kk = 0; kk < 4; ++kk){
      ah[gt][kk] = *(const bf16x8*)(pa + kk*32);
      al[gt][kk] = *(const bf16x8*)(pb + kk*32);
    }
  }

  const __bf16* bhp = wth + (size_t)(c0w >> 4)*2048 + lane*8;
  const __bf16* blp = wtl + (size_t)(c0w >> 4)*2048 + lane*8;
  const float* bp = bfc + c0w + kq*4;
  float (*stw)[68] = st[wave];

  const int srow = lane >> 4;                     // flush: 4 rows/instr
  const int scol = (lane & 15)*4;

  #pragma unroll 1
  for (int grp = 0; grp < 8; ++grp){              // 8 groups x 4 col-iters
    #pragma unroll
    for (int itg = 0; itg < 4; ++itg){
      bf16x8 bh[4], bl[4];
      #pragma unroll
      for (int kk = 0; kk < 4; ++kk){
        bh[kk] = *(const bf16x8*)(bhp + kk*512);
        bl[kk] = *(const bf16x8*)(blp + kk*512);
      }
      f32x4 q0 = {0.f,0.f,0.f,0.f}, q1 = {0.f,0.f,0.f,0.f};
      #pragma unroll
      for (int kk = 0; kk < 4; ++kk){
        q0 = __builtin_amdgcn_mfma_f32_16x16x32_bf16(bh[kk], ah[0][kk], q0, 0,0,0);
        q1 = __builtin_amdgcn_mfma_f32_16x16x32_bf16(bh[kk], ah[1][kk], q1, 0,0,0);
        q0 = __builtin_amdgcn_mfma_f32_16x16x32_bf16(bl[kk], ah[0][kk], q0, 0,0,0);
        q1 = __builtin_amdgcn_mfma_f32_16x16x32_bf16(bl[kk], ah[1][kk], q1, 0,0,0);
        q0 = __builtin_amdgcn_mfma_f32_16x16x32_bf16(bh[kk], al[0][kk], q0, 0,0,0);
        q1 = __builtin_amdgcn_mfma_f32_16x16x32_bf16(bh[kk], al[1][kk], q1, 0,0,0);
      }
      const float4 b4 = *(const float4*)bp;
      float4 v;
      v.x = q0[0]+b4.x; v.y = q0[1]+b4.y; v.z = q0[2]+b4.z; v.w = q0[3]+b4.w;
      *(float4*)&stw[lc][itg*16 + kq*4] = v;
      v.x = q1[0]+b4.x; v.y = q1[1]+b4.y; v.z = q1[2]+b4.z; v.w = q1[3]+b4.w;
      *(float4*)&stw[16 + lc][itg*16 + kq*4] = v;
      bhp += 2048; blp += 2048; bp += 16;
    }
    // flush 32 rows x 64 cols: 8 instrs, each 4 rows x 256B contiguous
    const int cbase = c0w + grp*64;
    #pragma unroll
    for (int r = 0; r < 8; ++r){
      const int row = r*4 + srow;
      const float4 v = *(const float4*)&stw[row][scol];
      *(float4*)&out[(size_t)(g0 + row)*FCO + cbase + scol] = v;
    }
  }
}

// ---------------- launch ----------------

extern "C" void kernel_launch(void* const* d_in, const int* in_sizes, int n_in,
                              void* d_out, int out_size, void* d_ws, size_t ws_size,
                              hipStream_t stream){
  const float* x   = (const float*)d_in[0];
  const int*   ei  = (const int*)d_in[1];   // [2, E] int32 (jax x64 off)
  const float* W1  = (const float*)d_in[3];
  const float* b1  = (const float*)d_in[4];
  const float* W2  = (const float*)d_in[5];
  const float* b2  = (const float*)d_in[6];
  const float* Wfc = (const float*)d_in[7];
  const float* bfc = (const float*)d_in[8];
  float* out = (float*)d_out;
  const int E = in_sizes[1] / 2;

  // workspace layout — same region bounds as R25 (cursor region now unused)
  float* bufA   = (float*)d_ws;                      // 33.5 MB region
  float* bufB   = bufA + (size_t)NODES*CH;           // 33.5 MB region
  float* dinv   = bufB + (size_t)NODES*CH;           // 256 KB
  int*   deg    = (int*)(dinv + NODES);              // 256 KB
  int*   cstart = deg + NODES;                       // NODES+1 (+256 reserve)
  int*   cursor = cstart + NODES + 256;              // (unused now)
  int*   bsums  = cursor + NODES;                    // 1 KB
  int*   ssrc   = bsums + 256;                       // 4 MB
  __bf16* phi   = (__bf16*)(ssrc + E);               // 256 KB
  __bf16* plo   = phi + (size_t)NGRAPH*CH;           // 256 KB

  __bf16* hwb = (__bf16*)bufA;                       // gemm out (bf16), 16.8 MB
  __bf16* hbb = (__bf16*)bufB;                       // agg out (bf16, relu'd), 16.8 MB
  __bf16* wth = (__bf16*)bufA;                       // 16.78 MB (after hwb dead)
  __bf16* wtl = wth + (size_t)FCO*CH;                // 16.78 MB

  const int* esrc = ei;
  const int* edst = ei + E;

  k_zero1  <<<NODES/1024,  256, 0, stream>>>(deg);
  k_degree <<<(E+255)/256, 256, 0, stream>>>(edst, deg, E);
  k_scan1  <<<NODES/256,   256, 0, stream>>>(deg, cstart, bsums, dinv);
  k_scan2  <<<1,           256, 0, stream>>>(bsums);
  k_scan3  <<<NODES/256,   256, 0, stream>>>(cstart, bsums, E);
  k_scatter<<<(E+255)/256, 256, 0, stream>>>(esrc, edst, cstart, ssrc, E);
  // cstart now holds END offsets; k_agg uses start = cend - deg

  k_gemm128<0><<<NODES/128, 256, 0, stream>>>(x,   W1, hwb);  // hwb = bf16(x@W1)
  k_agg       <<<NODES/16, 256, 0, stream>>>(hwb, dinv, cstart, deg, ssrc, b1, hbb);
  k_gemm128<1><<<NODES/128, 256, 0, stream>>>(hbb, W2, hwb);  // hwb = bf16(hbb@W2)
  k_agg       <<<NODES/16, 256, 0, stream>>>(hwb, dinv, cstart, deg, ssrc, b2, hbb);

  // hwb dead -> fragment-ordered split-bf16 Wfc reuses bufA
  k_cvt_wfc <<<FCO/64, 256, 0, stream>>>(Wfc, wth, wtl);
  k_pool    <<<NGRAPH, CH, 0, stream>>>(hbb, phi, plo);
  k_fc_mfma <<<dim3(NGRAPH/32, 32), 256, 0, stream>>>(phi, plo, wth, wtl, bfc, out);
}

// Round 27
// 385.849 us; speedup vs baseline: 1.0372x; 1.0372x over previous
//
#include <hip/hip_runtime.h>
#include <hip/hip_bf16.h>
#include <cstdint>

#define NODES  65536
#define CH     128
#define NGRAPH 1024
#define PGRAPH 64
#define FCO    65536

typedef __bf16 bf16x8 __attribute__((ext_vector_type(8)));
typedef __bf16 bf16x4 __attribute__((ext_vector_type(4)));
typedef float  f32x4  __attribute__((ext_vector_type(4)));

__device__ __forceinline__ float bflo(unsigned u){ return __uint_as_float(u << 16); }
__device__ __forceinline__ float bfhi(unsigned u){ return __uint_as_float(u & 0xffff0000u); }

// ---------------- graph preprocessing ----------------

__global__ void k_zero2(int* __restrict__ a, int* __restrict__ b){
  const int i = blockIdx.x*256 + threadIdx.x;
  ((int4*)a)[i] = make_int4(0,0,0,0);
  ((int4*)b)[i] = make_int4(0,0,0,0);
}

__global__ void k_degree(const int* __restrict__ dst, int* __restrict__ deg, int E){
  int e = blockIdx.x*256 + threadIdx.x;
  if (e < E) atomicAdd(&deg[dst[e]], 1);
}

__global__ void k_dinv(const int* __restrict__ deg, float* __restrict__ dinv){
  int i = blockIdx.x*256 + threadIdx.x;
  dinv[i] = 1.0f / sqrtf((float)(deg[i] + 1));   // self-loop -> deg+1 >= 1
}

__global__ void k_scan1(const int* __restrict__ deg, int* __restrict__ excl,
                        int* __restrict__ bsums){
  __shared__ int tmp[256];
  const int t = threadIdx.x;
  const int gid = blockIdx.x*256 + t;
  const int v = deg[gid];
  tmp[t] = v;
  __syncthreads();
  #pragma unroll
  for (int off = 1; off < 256; off <<= 1){
    int x = (t >= off) ? tmp[t-off] : 0;
    __syncthreads();
    tmp[t] += x;
    __syncthreads();
  }
  excl[gid] = tmp[t] - v;
  if (t == 255) bsums[blockIdx.x] = tmp[255];
}

__global__ void k_scan2(int* __restrict__ bsums){
  __shared__ int tmp[256];
  const int t = threadIdx.x;
  const int v = bsums[t];
  tmp[t] = v;
  __syncthreads();
  #pragma unroll
  for (int off = 1; off < 256; off <<= 1){
    int x = (t >= off) ? tmp[t-off] : 0;
    __syncthreads();
    tmp[t] += x;
    __syncthreads();
  }
  bsums[t] = tmp[t] - v;   // exclusive
}

__global__ void k_scan3(int* __restrict__ cstart, const int* __restrict__ bsums, int E){
  const int gid = blockIdx.x*256 + threadIdx.x;
  cstart[gid] += bsums[blockIdx.x];
  if (gid == 0) cstart[NODES] = E;
}

__global__ void k_scatter(const int* __restrict__ src, const int* __restrict__ dst,
                          const int* __restrict__ cstart, int* __restrict__ cursor,
                          int* __restrict__ ssrc, int E){
  int e = blockIdx.x*256 + threadIdx.x;
  if (e >= E) return;
  const int d = dst[e];
  const int p = cstart[d] + atomicAdd(&cursor[d], 1);
  ssrc[p] = src[e];
}

// ---------------- GEMM: C[n x 128] = A[n x 128] @ W[128 x 128], bf16 out ----------
template<int ABF>
__global__ __launch_bounds__(256)
void k_gemm128(const void* __restrict__ Av, const float* __restrict__ W,
               __bf16* __restrict__ Cout){
  __shared__ float As[128][36];
  __shared__ float Ws[32][160];
  const int t  = threadIdx.x;
  const int r0 = blockIdx.x * 128;
  const int q  = t & 3;
  const int rp = t >> 2;

  float acc0[32], acc1[32];
  #pragma unroll
  for (int j = 0; j < 32; ++j){ acc0[j] = 0.f; acc1[j] = 0.f; }

  for (int kc = 0; kc < 128; kc += 32){
    {
      const int row = t >> 1, u = t & 1;
      float* asp = &As[row][u*16];
      if (ABF){
        const __bf16* ap = (const __bf16*)Av + (size_t)(r0+row)*CH + kc + u*16;
        const bf16x8 v0 = *(const bf16x8*)ap;
        const bf16x8 v1 = *(const bf16x8*)(ap + 8);
        #pragma unroll
        for (int j = 0; j < 8; ++j){ asp[j] = (float)v0[j]; asp[8+j] = (float)v1[j]; }
      } else {
        const float* ap = (const float*)Av + (size_t)(r0+row)*CH + kc + u*16;
        #pragma unroll
        for (int i = 0; i < 4; ++i)
          *(float4*)(asp + 4*i) = *(const float4*)(ap + 4*i);
      }
    }
    {
      const int kk = t >> 3, u = t & 7;
      const float* wp = W + (size_t)(kc+kk)*CH + u*16;
      float* wsp = &Ws[kk][(u>>1)*40 + (u&1)*16];
      #pragma unroll
      for (int i = 0; i < 4; ++i)
        *(float4*)(wsp + 4*i) = *(const float4*)(wp + 4*i);
    }
    __syncthreads();

    #pragma unroll
    for (int kk4 = 0; kk4 < 8; ++kk4){
      const float4 a0 = *(const float4*)&As[rp][kk4*4];
      const float4 a1 = *(const float4*)&As[rp+64][kk4*4];
      const float a0f[4] = {a0.x, a0.y, a0.z, a0.w};
      const float a1f[4] = {a1.x, a1.y, a1.z, a1.w};
      #pragma unroll
      for (int kk = 0; kk < 4; ++kk){
        const float av0 = a0f[kk], av1 = a1f[kk];
        #pragma unroll
        for (int j4 = 0; j4 < 8; ++j4){
          const float4 w = *(const float4*)&Ws[kk4*4+kk][q*40 + j4*4];
          acc0[j4*4+0] = fmaf(av0, w.x, acc0[j4*4+0]);
          acc0[j4*4+1] = fmaf(av0, w.y, acc0[j4*4+1]);
          acc0[j4*4+2] = fmaf(av0, w.z, acc0[j4*4+2]);
          acc0[j4*4+3] = fmaf(av0, w.w, acc0[j4*4+3]);
          acc1[j4*4+0] = fmaf(av1, w.x, acc1[j4*4+0]);
          acc1[j4*4+1] = fmaf(av1, w.y, acc1[j4*4+1]);
          acc1[j4*4+2] = fmaf(av1, w.z, acc1[j4*4+2]);
          acc1[j4*4+3] = fmaf(av1, w.w, acc1[j4*4+3]);
        }
      }
    }
    __syncthreads();
  }

  __bf16* c0 = Cout + (size_t)(r0+rp)*CH    + q*32;
  __bf16* c1 = Cout + (size_t)(r0+rp+64)*CH + q*32;
  #pragma unroll
  for (int j4 = 0; j4 < 8; ++j4){
    bf16x4 v0, v1;
    #pragma unroll
    for (int e = 0; e < 4; ++e){ v0[e] = (__bf16)acc0[j4*4+e]; v1[e] = (__bf16)acc1[j4*4+e]; }
    *(bf16x4*)(c0 + j4*4) = v0;
    *(bf16x4*)(c1 + j4*4) = v1;
  }
}

// ---------------- CSR aggregation, fused bias+relu, bf16 in/out (R19-exact) ----------
__global__ __launch_bounds__(256)
void k_agg(const __bf16* __restrict__ hw, const float* __restrict__ dinv,
           const int* __restrict__ start, const int* __restrict__ srcs,
           const float* __restrict__ bias, __bf16* __restrict__ outp){
  const int l = threadIdx.x & 63, wave = threadIdx.x >> 6;
  const int n = l >> 4;                    // sub-node 0..3
  const int q = l & 15;                    // lane within node
  const int i = blockIdx.x*16 + wave*4 + n;
  const int c = q*8;
  const float di = dinv[i];

  const uint4 hs = *(const uint4*)&hw[(size_t)i*CH + c];
  float acc[8];
  acc[0] = di*bflo(hs.x); acc[1] = di*bfhi(hs.x);
  acc[2] = di*bflo(hs.y); acc[3] = di*bfhi(hs.y);
  acc[4] = di*bflo(hs.z); acc[5] = di*bfhi(hs.z);
  acc[6] = di*bflo(hs.w); acc[7] = di*bfhi(hs.w);

  int p = start[i];
  const int p1 = start[i+1];
  for (; p + 3 < p1; p += 4){
    const int s0 = srcs[p], s1 = srcs[p+1], s2 = srcs[p+2], s3 = srcs[p+3];
    const float w0 = dinv[s0], w1 = dinv[s1], w2 = dinv[s2], w3 = dinv[s3];
    const uint4 r0 = *(const uint4*)&hw[(size_t)s0*CH + c];
    const uint4 r1 = *(const uint4*)&hw[(size_t)s1*CH + c];
    const uint4 r2 = *(const uint4*)&hw[(size_t)s2*CH + c];
    const uint4 r3 = *(const uint4*)&hw[(size_t)s3*CH + c];
    acc[0]+=w0*bflo(r0.x); acc[1]+=w0*bfhi(r0.x); acc[2]+=w0*bflo(r0.y); acc[3]+=w0*bfhi(r0.y);
    acc[4]+=w0*bflo(r0.z); acc[5]+=w0*bfhi(r0.z); acc[6]+=w0*bflo(r0.w); acc[7]+=w0*bfhi(r0.w);
    acc[0]+=w1*bflo(r1.x); acc[1]+=w1*bfhi(r1.x); acc[2]+=w1*bflo(r1.y); acc[3]+=w1*bfhi(r1.y);
    acc[4]+=w1*bflo(r1.z); acc[5]+=w1*bfhi(r1.z); acc[6]+=w1*bflo(r1.w); acc[7]+=w1*bfhi(r1.w);
    acc[0]+=w2*bflo(r2.x); acc[1]+=w2*bfhi(r2.x); acc[2]+=w2*bflo(r2.y); acc[3]+=w2*bfhi(r2.y);
    acc[4]+=w2*bflo(r2.z); acc[5]+=w2*bfhi(r2.z); acc[6]+=w2*bflo(r2.w); acc[7]+=w2*bfhi(r2.w);
    acc[0]+=w3*bflo(r3.x); acc[1]+=w3*bfhi(r3.x); acc[2]+=w3*bflo(r3.y); acc[3]+=w3*bfhi(r3.y);
    acc[4]+=w3*bflo(r3.z); acc[5]+=w3*bfhi(r3.z); acc[6]+=w3*bflo(r3.w); acc[7]+=w3*bfhi(r3.w);
  }
  for (; p < p1; ++p){
    const int s = srcs[p];
    const float w = dinv[s];
    const uint4 r = *(const uint4*)&hw[(size_t)s*CH + c];
    acc[0]+=w*bflo(r.x); acc[1]+=w*bfhi(r.x); acc[2]+=w*bflo(r.y); acc[3]+=w*bfhi(r.y);
    acc[4]+=w*bflo(r.z); acc[5]+=w*bfhi(r.z); acc[6]+=w*bflo(r.w); acc[7]+=w*bfhi(r.w);
  }

  const float4 b0 = *(const float4*)&bias[c];
  const float4 b1 = *(const float4*)&bias[c+4];
  const float bb[8] = {b0.x,b0.y,b0.z,b0.w,b1.x,b1.y,b1.z,b1.w};
  bf16x8 o;
  #pragma unroll
  for (int k = 0; k < 8; ++k)
    o[k] = (__bf16)fmaxf(di*acc[k] + bb[k], 0.f);
  *(bf16x8*)&outp[(size_t)i*CH + c] = o;
}

// ---------------- pool: pooled[g] = mean over 64 nodes (relu already applied) ------
__global__ void k_pool(const __bf16* __restrict__ h,
                       __bf16* __restrict__ phi, __bf16* __restrict__ plo){
  const int g = blockIdx.x, c = threadIdx.x;
  float acc = 0.f;
  const __bf16* hp = h + (size_t)g*PGRAPH*CH + c;
  #pragma unroll 4
  for (int i = 0; i < PGRAPH; ++i) acc += (float)hp[i*CH];
  const float v = acc * (1.0f/64.0f);
  const __bf16 hv = (__bf16)v;
  phi[g*CH + c] = hv;
  plo[g*CH + c] = (__bf16)(v - (float)hv);
}

// ---------------- Wfc -> split-bf16 in FRAGMENT order (tile stride 2048) ----------------
__global__ __launch_bounds__(256)
void k_cvt_wfc(const float* __restrict__ Wfc, __bf16* __restrict__ wth,
               __bf16* __restrict__ wtl){
  __shared__ float ls[128][65];
  const int t  = threadIdx.x;
  const int c0 = blockIdx.x*64;

  #pragma unroll 8
  for (int it = 0; it < 32; ++it){
    const int row = it*4 + (t>>6);
    ls[row][t&63] = Wfc[(size_t)row*FCO + c0 + (t&63)];
  }
  __syncthreads();

  const int col = t>>2, q = t&3;
  const int tg  = (c0>>4) + (col>>4);
  const int lc  = col & 15;
  __bf16* dh = wth + (size_t)tg*2048 + q*512 + lc*8;
  __bf16* dl = wtl + (size_t)tg*2048 + q*512 + lc*8;
  #pragma unroll
  for (int i = 0; i < 4; ++i){
    bf16x8 h8, l8;
    #pragma unroll
    for (int j = 0; j < 8; ++j){
      const float v = ls[q*32 + i*8 + j][col];
      const __bf16 hv = (__bf16)v;
      h8[j] = hv;
      l8[j] = (__bf16)(v - (float)hv);
    }
    *(bf16x8*)(dh + i*128) = h8;
    *(bf16x8*)(dl + i*128) = l8;
  }
}

// ---------------- FC via split-bf16 MFMA, 32 graphs/wave + LDS-staged stores --------
__global__ __launch_bounds__(256, 4)
void k_fc_mfma(const __bf16* __restrict__ phi, const __bf16* __restrict__ plo,
               const __bf16* __restrict__ wth, const __bf16* __restrict__ wtl,
               const float* __restrict__ bfc, float* __restrict__ out){
  __shared__ float st[4][32][68];                 // 34.8 KB
  const int t    = threadIdx.x;
  const int lane = t & 63, wave = t >> 6;
  const int lc   = lane & 15, kq = lane >> 4;
  const int g0   = blockIdx.x*32;                 // x = graph-tile (fast dim)
  const int c0w  = blockIdx.y*2048 + wave*512;    // y = col-range

  bf16x8 ah[2][4], al[2][4];                      // 64 VGPR
  #pragma unroll
  for (int gt = 0; gt < 2; ++gt){
    const __bf16* pa = phi + (size_t)(g0 + gt*16 + lc)*CH + kq*8;
    const __bf16* pb = plo + (size_t)(g0 + gt*16 + lc)*CH + kq*8;
    #pragma unroll
    for (int kk = 0; kk < 4; ++kk){
      ah[gt][kk] = *(const bf16x8*)(pa + kk*32);
      al[gt][kk] = *(const bf16x8*)(pb + kk*32);
    }
  }

  const __bf16* bhp = wth + (size_t)(c0w >> 4)*2048 + lane*8;
  const __bf16* blp = wtl + (size_t)(c0w >> 4)*2048 + lane*8;
  const float* bp = bfc + c0w + kq*4;
  float (*stw)[68] = st[wave];

  const int srow = lane >> 4;                     // flush: 4 rows/instr
  const int scol = (lane & 15)*4;

  #pragma unroll 1
  for (int grp = 0; grp < 8; ++grp){              // 8 groups x 4 col-iters
    #pragma unroll
    for (int itg = 0; itg < 4; ++itg){
      bf16x8 bh[4], bl[4];
      #pragma unroll
      for (int kk = 0; kk < 4; ++kk){
        bh[kk] = *(const bf16x8*)(bhp + kk*512);
        bl[kk] = *(const bf16x8*)(blp + kk*512);
      }
      f32x4 q0 = {0.f,0.f,0.f,0.f}, q1 = {0.f,0.f,0.f,0.f};
      #pragma unroll
      for (int kk = 0; kk < 4; ++kk){
        q0 = __builtin_amdgcn_mfma_f32_16x16x32_bf16(bh[kk], ah[0][kk], q0, 0,0,0);
        q1 = __builtin_amdgcn_mfma_f32_16x16x32_bf16(bh[kk], ah[1][kk], q1, 0,0,0);
        q0 = __builtin_amdgcn_mfma_f32_16x16x32_bf16(bl[kk], ah[0][kk], q0, 0,0,0);
        q1 = __builtin_amdgcn_mfma_f32_16x16x32_bf16(bl[kk], ah[1][kk], q1, 0,0,0);
        q0 = __builtin_amdgcn_mfma_f32_16x16x32_bf16(bh[kk], al[0][kk], q0, 0,0,0);
        q1 = __builtin_amdgcn_mfma_f32_16x16x32_bf16(bh[kk], al[1][kk], q1, 0,0,0);
      }
      const float4 b4 = *(const float4*)bp;
      float4 v;
      v.x = q0[0]+b4.x; v.y = q0[1]+b4.y; v.z = q0[2]+b4.z; v.w = q0[3]+b4.w;
      *(float4*)&stw[lc][itg*16 + kq*4] = v;
      v.x = q1[0]+b4.x; v.y = q1[1]+b4.y; v.z = q1[2]+b4.z; v.w = q1[3]+b4.w;
      *(float4*)&stw[16 + lc][itg*16 + kq*4] = v;
      bhp += 2048; blp += 2048; bp += 16;
    }
    // flush 32 rows x 64 cols: 8 instrs, each 4 rows x 256B contiguous
    const int cbase = c0w + grp*64;
    #pragma unroll
    for (int r = 0; r < 8; ++r){
      const int row = r*4 + srow;
      const float4 v = *(const float4*)&stw[row][scol];
      *(float4*)&out[(size_t)(g0 + row)*FCO + cbase + scol] = v;
    }
  }
}

// ---------------- launch ----------------

extern "C" void kernel_launch(void* const* d_in, const int* in_sizes, int n_in,
                              void* d_out, int out_size, void* d_ws, size_t ws_size,
                              hipStream_t stream){
  const float* x   = (const float*)d_in[0];
  const int*   ei  = (const int*)d_in[1];   // [2, E] int32 (jax x64 off)
  const float* W1  = (const float*)d_in[3];
  const float* b1  = (const float*)d_in[4];
  const float* W2  = (const float*)d_in[5];
  const float* b2  = (const float*)d_in[6];
  const float* Wfc = (const float*)d_in[7];
  const float* bfc = (const float*)d_in[8];
  float* out = (float*)d_out;
  const int E = in_sizes[1] / 2;

  // workspace layout — R25-exact (best measured: 390.3 us)
  float* bufA   = (float*)d_ws;                      // 33.5 MB region
  float* bufB   = bufA + (size_t)NODES*CH;           // 33.5 MB region
  float* dinv   = bufB + (size_t)NODES*CH;           // 256 KB
  int*   deg    = (int*)(dinv + NODES);              // 256 KB
  int*   cstart = deg + NODES;                       // NODES+1 (+256 reserve)
  int*   cursor = cstart + NODES + 256;              // 256 KB
  int*   bsums  = cursor + NODES;                    // 1 KB
  int*   ssrc   = bsums + 256;                       // 4 MB
  __bf16* phi   = (__bf16*)(ssrc + E);               // 256 KB
  __bf16* plo   = phi + (size_t)NGRAPH*CH;           // 256 KB

  __bf16* hwb = (__bf16*)bufA;                       // gemm out (bf16), 16.8 MB
  __bf16* hbb = (__bf16*)bufB;                       // agg out (bf16, relu'd), 16.8 MB
  __bf16* wth = (__bf16*)bufA;                       // 16.78 MB (after hwb dead)
  __bf16* wtl = wth + (size_t)FCO*CH;                // 16.78 MB

  const int* esrc = ei;
  const int* edst = ei + E;

  k_zero2  <<<NODES/1024,  256, 0, stream>>>(deg, cursor);
  k_degree <<<(E+255)/256, 256, 0, stream>>>(edst, deg, E);
  k_dinv   <<<NODES/256,   256, 0, stream>>>(deg, dinv);
  k_scan1  <<<NODES/256,   256, 0, stream>>>(deg, cstart, bsums);
  k_scan2  <<<1,           256, 0, stream>>>(bsums);
  k_scan3  <<<NODES/256,   256, 0, stream>>>(cstart, bsums, E);
  k_scatter<<<(E+255)/256, 256, 0, stream>>>(esrc, edst, cstart, cursor, ssrc, E);

  k_gemm128<0><<<NODES/128, 256, 0, stream>>>(x,   W1, hwb);  // hwb = bf16(x@W1)
  k_agg       <<<NODES/16, 256, 0, stream>>>(hwb, dinv, cstart, ssrc, b1, hbb);
  k_gemm128<1><<<NODES/128, 256, 0, stream>>>(hbb, W2, hwb);  // hwb = bf16(hbb@W2)
  k_agg       <<<NODES/16, 256, 0, stream>>>(hwb, dinv, cstart, ssrc, b2, hbb);

  // hwb dead -> fragment-ordered split-bf16 Wfc reuses bufA
  k_cvt_wfc <<<FCO/64, 256, 0, stream>>>(Wfc, wth, wtl);
  k_pool    <<<NGRAPH, CH, 0, stream>>>(hbb, phi, plo);
  k_fc_mfma <<<dim3(NGRAPH/32, 32), 256, 0, stream>>>(phi, plo, wth, wtl, bfc, out);
}